// Round 4
// baseline (532.558 us; speedup 1.0000x reference)
//
#include <hip/hip_runtime.h>
#include <hip/hip_bf16.h>
#include <math.h>

#define D 128
#define S 256
#define ROWS 128               // rows per block = 4 waves x 32
#define LOG_S 5.545177444479562f
#define SCALE_EXP2 14.42695040888963f   // 10 * log2(e): exp(10*cos) == exp2(acc)

typedef __attribute__((ext_vector_type(8)))  short    short8;
typedef __attribute__((ext_vector_type(8)))  __bf16   bf16x8;
typedef __attribute__((ext_vector_type(16))) float    floatx16;

typedef const __attribute__((address_space(1))) void gas_void;
typedef __attribute__((address_space(3))) void las_void;

#if __has_builtin(__builtin_amdgcn_exp2f)
#define EXP2(x) __builtin_amdgcn_exp2f(x)
#else
#define EXP2(x) exp2f(x)
#endif

__device__ __forceinline__ unsigned short f2bf(float x) {
  __hip_bfloat16 h = __float2bfloat16(x);   // RNE
  return *(unsigned short*)&h;
}

__device__ __forceinline__ float dot4(float4 a, float4 b) {
  return a.x*b.x + a.y*b.y + a.z*b.z + a.w*b.w;
}

// ---- normalize negatives (eps=1e-8), fold 10*log2e, emit PRE-SWIZZLED bf16.
// 4 chunks of 64 negs, 16 KB each; neg nr stores 16B-unit lu at (lu ^ (nr&15)).
__global__ void neg_norm_kernel(const float* __restrict__ emb,
                                const int* __restrict__ negidx,
                                unsigned short* __restrict__ negsw) {
  int s = blockIdx.x;       // 0..S-1
  int L = threadIdx.x;      // 0..63, elements 2L, 2L+1
  long idx = (long)negidx[s];
  float2 v = *(const float2*)(emb + idx * D + L * 2);
  float ss = v.x * v.x + v.y * v.y;
#pragma unroll
  for (int off = 1; off < 64; off <<= 1) ss += __shfl_xor(ss, off);
  float sc = SCALE_EXP2 / fmaxf(sqrtf(ss), 1e-8f);
  int chunk = s >> 6, nr = s & 63;
  int lu = L >> 2, pos = (L & 3) * 2;
  int u = lu ^ (nr & 15);
  ushort2 o = make_ushort2(f2bf(v.x * sc), f2bf(v.y * sc));
  *(ushort2*)(negsw + chunk * 8192 + nr * 128 + u * 8 + pos) = o;
}

// LDS 32 KB: two 16 KB negative-chunk buffers (double-buffered).
// Rows never touch LDS: each lane builds its MFMA A-fragment in registers
// straight from global (lane ln owns row w*32+ln; q-half owns k-slices 2ki+q).
__global__ __launch_bounds__(256, 4)
void hyper_main(const float* __restrict__ emb,
                const int* __restrict__ posidx,
                const unsigned short* __restrict__ negsw,
                double* __restrict__ acc,
                int N) {
  __shared__ __align__(16) char smem[32768];

  const int t = threadIdx.x;
  const int lane = t & 63;
  const int w = t >> 6;        // wave 0..3
  const int q = lane >> 5;     // half-wave
  const int ln = lane & 31;
  const long rbase = (long)blockIdx.x * ROWS;

  // ---- issue chunk-0 negative staging (flies during the whole row pass) ----
  {
    const char* g = (const char*)negsw + w * 4096 + lane * 16;
    char* l = smem + w * 4096;
#pragma unroll
    for (int i = 0; i < 4; ++i)
      __builtin_amdgcn_global_load_lds((gas_void*)(g + i * 1024),
                                       (las_void*)(l + i * 1024), 16, 0, 0);
  }

  // ---- register staging: row + positive gather, one cross-half shuffle ----
  const long n = rbase + w * 32 + ln;
  const bool valid = (n < (long)N);
  long pi = 0;
  if (valid) pi = (long)posidx[n];

  float4 rv[8][2];
  float ssv = 0.f, ssp = 0.f, dp = 0.f;
#pragma unroll
  for (int ki = 0; ki < 8; ++ki) {
    int off = (2 * ki + q) * 8;                 // my k-slice of the row
    float4 a0 = make_float4(0.f,0.f,0.f,0.f), a1 = a0, p0 = a0, p1 = a0;
    if (valid) {
      a0 = *(const float4*)(emb + n * D + off);
      a1 = *(const float4*)(emb + n * D + off + 4);
      p0 = *(const float4*)(emb + pi * D + off);
      p1 = *(const float4*)(emb + pi * D + off + 4);
    }
    rv[ki][0] = a0; rv[ki][1] = a1;
    ssv += dot4(a0, a0) + dot4(a1, a1);
    ssp += dot4(p0, p0) + dot4(p1, p1);
    dp  += dot4(a0, p0) + dot4(a1, p1);
  }
  // lanes ln and ln+32 hold complementary halves of the same row
  ssv += __shfl_xor(ssv, 32);
  ssp += __shfl_xor(ssp, 32);
  dp  += __shfl_xor(dp,  32);

  float inv8 = 1.0f / fmaxf(sqrtf(ssv), 1e-8f);   // cosine-path eps
  short8 afrag[8];
#pragma unroll
  for (int ki = 0; ki < 8; ++ki) {
    float4 a0 = rv[ki][0], a1 = rv[ki][1];
    short8 t8;
    t8[0] = (short)f2bf(a0.x * inv8); t8[1] = (short)f2bf(a0.y * inv8);
    t8[2] = (short)f2bf(a0.z * inv8); t8[3] = (short)f2bf(a0.w * inv8);
    t8[4] = (short)f2bf(a1.x * inv8); t8[5] = (short)f2bf(a1.y * inv8);
    t8[6] = (short)f2bf(a1.z * inv8); t8[7] = (short)f2bf(a1.w * inv8);
    afrag[ki] = t8;
  }

  float possum = 0.f;
  if (q == 0 && valid) {
    float invv = 1.0f / fmaxf(sqrtf(ssv), 1e-12f);  // F.normalize eps
    float invp = 1.0f / fmaxf(sqrtf(ssp), 1e-12f);
    possum = dp * invv * invp * 10.0f;
  }

  // ---- negatives: 4 chunks of 64, double-buffered, plain exp2-sum ----
  float se[16];
#pragma unroll
  for (int i = 0; i < 16; ++i) se[i] = 0.f;

  const int ulocal = (ln & 15);
  for (int c = 0; c < 4; ++c) {
    __syncthreads();   // drains loads for chunk c (issued long ago)
    if (c < 3) {       // prefetch chunk c+1 into the other buffer
      const char* g = (const char*)negsw + (c + 1) * 16384 + w * 4096 + lane * 16;
      char* l = smem + ((c + 1) & 1) * 16384 + w * 4096;
#pragma unroll
      for (int i = 0; i < 4; ++i)
        __builtin_amdgcn_global_load_lds((gas_void*)(g + i * 1024),
                                         (las_void*)(l + i * 1024), 16, 0, 0);
    }
    const unsigned short* buf = (const unsigned short*)(smem + (c & 1) * 16384);

    floatx16 acc0 = {};
    floatx16 acc1 = {};
#pragma unroll
    for (int ki = 0; ki < 8; ++ki) {
      int lu = 2 * ki + q;
      int u8 = (lu ^ ulocal) * 8;
      short8 b0 = *(const short8*)&buf[ln * 128 + u8];
      short8 b1 = *(const short8*)&buf[(ln + 32) * 128 + u8];
      acc0 = __builtin_amdgcn_mfma_f32_32x32x16_bf16(
          __builtin_bit_cast(bf16x8, afrag[ki]), __builtin_bit_cast(bf16x8, b0), acc0, 0, 0, 0);
      acc1 = __builtin_amdgcn_mfma_f32_32x32x16_bf16(
          __builtin_bit_cast(bf16x8, afrag[ki]), __builtin_bit_cast(bf16x8, b1), acc1, 0, 0, 0);
    }
#pragma unroll
    for (int rg = 0; rg < 16; ++rg)
      se[rg] += EXP2(acc0[rg]) + EXP2(acc1[rg]);
  }

  // ---- reduce exp-sums across the 32 columns of each half-wave ----
#pragma unroll
  for (int rg = 0; rg < 16; ++rg) {
    float sv = se[rg];
#pragma unroll
    for (int off = 1; off < 32; off <<= 1) sv += __shfl_xor(sv, off);
    se[rg] = sv;
  }

  float negsum = 0.f;
  if (ln == 0) {
#pragma unroll
    for (int rg = 0; rg < 16; ++rg) {
      int rr = w * 32 + (rg & 3) + 8 * (rg >> 2) + 4 * q;  // C/D row mapping
      long n2 = rbase + rr;
      if (n2 < (long)N) negsum += __logf(se[rg]) - LOG_S;
    }
  }

  // ---- block reduce -> one double atomic ----
  float local = negsum - possum;
#pragma unroll
  for (int off = 1; off < 64; off <<= 1) local += __shfl_xor(local, off);
  float* red = (float*)smem;   // buf0 region; last chunk read buf1 — disjoint
  if (lane == 0) red[w] = local;
  __syncthreads();
  if (t == 0) {
    double tot = (double)red[0] + (double)red[1] +
                 (double)red[2] + (double)red[3];
    atomicAdd(acc, tot);
  }
}

__global__ void finish_kernel(const double* __restrict__ acc,
                              float* __restrict__ out, int N) {
  out[0] = (float)(acc[0] / (double)N);
}

extern "C" void kernel_launch(void* const* d_in, const int* in_sizes, int n_in,
                              void* d_out, int out_size, void* d_ws, size_t ws_size,
                              hipStream_t stream) {
  const float* emb  = (const float*)d_in[0];
  const int* posidx = (const int*)d_in[1];
  const int* negidx = (const int*)d_in[2];
  int N = in_sizes[1];

  double* acc = (double*)d_ws;
  unsigned short* negsw = (unsigned short*)((char*)d_ws + 256);

  hipMemsetAsync(d_ws, 0, 256, stream);
  neg_norm_kernel<<<S, 64, 0, stream>>>(emb, negidx, negsw);
  int grid = (N + ROWS - 1) / ROWS;
  hyper_main<<<grid, 256, 0, stream>>>(emb, posidx, negsw, acc, N);
  finish_kernel<<<1, 1, 0, stream>>>(acc, (float*)d_out, N);
}

// Round 5
// 505.796 us; speedup vs baseline: 1.0529x; 1.0529x over previous
//
#include <hip/hip_runtime.h>
#include <hip/hip_bf16.h>
#include <math.h>

#define D 128
#define S 256
#define ROWS 256               // rows per block = 8 waves x 32
#define LOG_S 5.545177444479562f
#define SCALE_EXP2 14.42695040888963f   // 10*log2(e): exp(10*cos) == exp2(acc*inv8)

typedef __attribute__((ext_vector_type(8)))  short    short8;
typedef __attribute__((ext_vector_type(8)))  __bf16   bf16x8;
typedef __attribute__((ext_vector_type(16))) float    floatx16;

typedef const __attribute__((address_space(1))) void gas_void;
typedef __attribute__((address_space(3))) void las_void;

#if __has_builtin(__builtin_amdgcn_exp2f)
#define EXP2(x) __builtin_amdgcn_exp2f(x)
#else
#define EXP2(x) exp2f(x)
#endif

__device__ __forceinline__ unsigned short f2bf(float x) {
  __hip_bfloat16 h = __float2bfloat16(x);   // RNE
  return *(unsigned short*)&h;
}

__device__ __forceinline__ float dot4(float4 a, float4 b) {
  return a.x*b.x + a.y*b.y + a.z*b.z + a.w*b.w;
}

// ---- normalize negatives (eps=1e-8), fold 10*log2e, emit the PRE-SWIZZLED
// 64 KB LDS image: row s stores 16B-unit lu at (lu ^ (s&15)). Also zeroes acc.
__global__ void neg_norm_kernel(const float* __restrict__ emb,
                                const int* __restrict__ negidx,
                                unsigned short* __restrict__ negsw,
                                double* __restrict__ acc) {
  int s = blockIdx.x;       // 0..S-1
  int L = threadIdx.x;      // 0..63, elements 2L, 2L+1
  if (s == 0 && L == 0) acc[0] = 0.0;   // runs before hyper_main (stream order)
  long idx = (long)negidx[s];
  float2 v = *(const float2*)(emb + idx * D + L * 2);
  float ss = v.x * v.x + v.y * v.y;
#pragma unroll
  for (int off = 1; off < 64; off <<= 1) ss += __shfl_xor(ss, off);
  float sc = SCALE_EXP2 / fmaxf(sqrtf(ss), 1e-8f);
  int lu = L >> 2, pos = (L & 3) * 2;
  int u = lu ^ (s & 15);
  ushort2 o = make_ushort2(f2bf(v.x * sc), f2bf(v.y * sc));
  *(ushort2*)(negsw + s * 128 + u * 8 + pos) = o;
}

// 512 threads = 8 waves x 32 rows. Entire negative set (64 KB) staged to LDS
// once per block; ONE barrier; then a fully barrier-free MFMA/exp2 march.
// Rows go straight from global to bf16 A-fragments (raw values — the per-row
// 1/|x| normalization commutes with the matmul and is applied post-MFMA).
__global__ __launch_bounds__(512, 4)    // 4 waves/EU = 2 blocks/CU (128 KB LDS)
void hyper_main(const float* __restrict__ emb,
                const int* __restrict__ posidx,
                const unsigned short* __restrict__ negsw,
                double* __restrict__ acc,
                int N) {
  __shared__ __align__(16) char smem[65536];

  const int t = threadIdx.x;
  const int lane = t & 63;
  const int w = t >> 6;        // wave 0..7
  const int q = lane >> 5;     // half-wave
  const int ln = lane & 31;
  const long rbase = (long)blockIdx.x * ROWS;

  // ---- stage ALL negatives (64 KB) async; lands during row staging ----
  {
    const char* g = (const char*)negsw + w * 1024 + lane * 16;
    char* l = smem + w * 1024;
#pragma unroll
    for (int i = 0; i < 8; ++i)
      __builtin_amdgcn_global_load_lds((gas_void*)(g + i * 8192),
                                       (las_void*)(l + i * 8192), 16, 0, 0);
  }

  // ---- rows: raw -> bf16 afrag immediately; norms + positive path fused ----
  const long n = rbase + w * 32 + ln;
  const bool valid = (n < (long)N);
  long pi = 0;
  if (valid) pi = (long)posidx[n];

  short8 afrag[8];
  float ssv = 0.f, ssp = 0.f, dp = 0.f;
#pragma unroll
  for (int ki = 0; ki < 8; ++ki) {
    int off = (2 * ki + q) * 8;                 // my 16-elem k-slice
    float4 a0 = make_float4(0.f,0.f,0.f,0.f), a1 = a0, p0 = a0, p1 = a0;
    if (valid) {
      a0 = *(const float4*)(emb + n * D + off);
      a1 = *(const float4*)(emb + n * D + off + 4);
      p0 = *(const float4*)(emb + pi * D + off);
      p1 = *(const float4*)(emb + pi * D + off + 4);
    }
    ssv += dot4(a0, a0) + dot4(a1, a1);
    ssp += dot4(p0, p0) + dot4(p1, p1);
    dp  += dot4(a0, p0) + dot4(a1, p1);
    short8 t8;
    t8[0] = (short)f2bf(a0.x); t8[1] = (short)f2bf(a0.y);
    t8[2] = (short)f2bf(a0.z); t8[3] = (short)f2bf(a0.w);
    t8[4] = (short)f2bf(a1.x); t8[5] = (short)f2bf(a1.y);
    t8[6] = (short)f2bf(a1.z); t8[7] = (short)f2bf(a1.w);
    afrag[ki] = t8;            // raw bf16 — no norm dependency, no fp32 hold
  }
  // lanes ln and ln+32 hold complementary halves of the same row
  ssv += __shfl_xor(ssv, 32);
  ssp += __shfl_xor(ssp, 32);
  dp  += __shfl_xor(dp,  32);

  float inv8 = 1.0f / fmaxf(sqrtf(ssv), 1e-8f);   // cosine-path eps
  float possum = 0.f;
  if (q == 0 && valid) {
    float invv = 1.0f / fmaxf(sqrtf(ssv), 1e-12f);  // F.normalize eps
    float invp = 1.0f / fmaxf(sqrtf(ssp), 1e-12f);
    possum = dp * invv * invp * 10.0f;
  }

  // per-accumulator-slot row scale, broadcast from the row's owner lane
  float srg[16];
#pragma unroll
  for (int rg = 0; rg < 16; ++rg)
    srg[rg] = __shfl(inv8, (rg & 3) + 8 * (rg >> 2) + 4 * q);

  __syncthreads();   // negs staged (loads drained); the ONLY compute barrier

  // ---- 8 column-chunks of 32 negs; barrier-free; plain exp2-sum ----
  const int ulocal = ln & 15;
  const unsigned short* buf = (const unsigned short*)smem;
  float se[16];
#pragma unroll
  for (int i = 0; i < 16; ++i) se[i] = 0.f;

#pragma unroll
  for (int g = 0; g < 8; ++g) {
    const unsigned short* col = buf + (g * 32 + ln) * 128;
    floatx16 a = {};
#pragma unroll
    for (int ki = 0; ki < 8; ++ki) {
      int u8 = ((2 * ki + q) ^ ulocal) * 8;
      short8 b = *(const short8*)&col[u8];
      a = __builtin_amdgcn_mfma_f32_32x32x16_bf16(
          __builtin_bit_cast(bf16x8, afrag[ki]), __builtin_bit_cast(bf16x8, b),
          a, 0, 0, 0);
    }
#pragma unroll
    for (int rg = 0; rg < 16; ++rg)
      se[rg] += EXP2(a[rg] * srg[rg]);
  }

  // ---- reduce exp-sums across the 32 columns of each half-wave ----
#pragma unroll
  for (int rg = 0; rg < 16; ++rg) {
    float sv = se[rg];
#pragma unroll
    for (int off = 1; off < 32; off <<= 1) sv += __shfl_xor(sv, off);
    se[rg] = sv;
  }

  float negsum = 0.f;
  if (ln == 0) {
#pragma unroll
    for (int rg = 0; rg < 16; ++rg) {
      int rr = w * 32 + (rg & 3) + 8 * (rg >> 2) + 4 * q;  // C/D row mapping
      long n2 = rbase + rr;
      if (n2 < (long)N) negsum += __logf(se[rg]) - LOG_S;
    }
  }

  // ---- block reduce -> one double atomic ----
  float local = negsum - possum;
#pragma unroll
  for (int off = 1; off < 64; off <<= 1) local += __shfl_xor(local, off);
  __syncthreads();             // all LDS neg reads done; safe to reuse smem
  float* red = (float*)smem;
  if (lane == 0) red[w] = local;
  __syncthreads();
  if (t == 0) {
    double tot = 0.0;
#pragma unroll
    for (int i = 0; i < 8; ++i) tot += (double)red[i];
    atomicAdd(acc, tot);
  }
}

__global__ void finish_kernel(const double* __restrict__ acc,
                              float* __restrict__ out, int N) {
  out[0] = (float)(acc[0] / (double)N);
}

extern "C" void kernel_launch(void* const* d_in, const int* in_sizes, int n_in,
                              void* d_out, int out_size, void* d_ws, size_t ws_size,
                              hipStream_t stream) {
  const float* emb  = (const float*)d_in[0];
  const int* posidx = (const int*)d_in[1];
  const int* negidx = (const int*)d_in[2];
  int N = in_sizes[1];

  double* acc = (double*)d_ws;
  unsigned short* negsw = (unsigned short*)((char*)d_ws + 256);

  neg_norm_kernel<<<S, 64, 0, stream>>>(emb, negidx, negsw, acc);
  int grid = (N + ROWS - 1) / ROWS;
  hyper_main<<<grid, 512, 0, stream>>>(emb, posidx, negsw, acc, N);
  finish_kernel<<<1, 1, 0, stream>>>(acc, (float*)d_out, N);
}